// Round 1
// baseline (67.893 us; speedup 1.0000x reference)
//
#include <hip/hip_runtime.h>
#include <math.h>

#define IW 256
#define IH 256
#define NG 1000
#define NSEG 4
#define SEG (NG / NSEG)         // 250 gaussians per wave-segment
#define TILE_W 16
#define TILE_H 4
#define TILES_X (IW / TILE_W)   // 16
#define TILES_Y (IH / TILE_H)   // 64
#define ALPHA_MAX 0.999f
#define LOG2_EPS -19.93157f     // log2(1e-6) cull threshold
#define LN2 0.6931471805599453f
#define INV_LN2 1.4426950408889634f

// ---------------------------------------------------------------------------
// Pass 1: per-gaussian derived parameters, computed ONCE (1000 threads).
// Previously every one of the 1024 tile-blocks recomputed all 1000 gaussians'
// params (7 transcendentals + ~40 VALU each) -> ~1M redundant evaluations
// dominating the instruction stream. Hoisted here; tile kernel culls with a
// single 16B load + 2 compares per gaussian.
//   ws layout: g0[NG] float4 = (cx, cy, rx, ry)       cull
//              g1[NG] float4 = (A,  B,  C,  lop)      exponent (log2 domain)
//              gc[NG] float  = col                    premapped sigmoid(rgb)
// Total 36 KB in d_ws.
// ---------------------------------------------------------------------------
__global__ __launch_bounds__(256) void precompute_kernel(
    const float* __restrict__ means,
    const float* __restrict__ quats,
    const float* __restrict__ scales,
    const float* __restrict__ rgbs,
    const float* __restrict__ opacities,
    float4* __restrict__ g0,
    float4* __restrict__ g1,
    float*  __restrict__ gc)
{
    const int n = blockIdx.x * 256 + threadIdx.x;
    if (n >= NG) return;

    float2 mu = ((const float2*)means)[n];
    float2 sc = ((const float2*)scales)[n];
    float q   = quats[n];
    float opa = opacities[n];
    float rgb = rgbs[n];

    float sq, cq;
    __sincosf(q, &sq, &cq);
    float sx2 = sc.x * sc.x, sy2 = sc.y * sc.y;
    float a11 = cq * cq * sx2 + sq * sq * sy2;
    float a12 = cq * sq * (sx2 - sy2);
    float a22 = sq * sq * sx2 + cq * cq * sy2;
    float det = a11 * a22 - a12 * a12;
    float inv = INV_LN2 / det;
    float A   = -0.5f * a22 * inv;
    float B   =          a12 * inv;
    float Cc  = -0.5f * a11 * inv;
    float op  = 1.0f / (1.0f + __expf(-opa));
    float lop = __log2f(op);
    float col = 1.0f / (1.0f + __expf(-rgb));

    float t  = fmaxf((lop - LOG2_EPS) * LN2, 0.0f);
    float rx = sqrtf(2.0f * a11 * t);
    float ry = sqrtf(2.0f * a22 * t);

    g0[n] = make_float4(mu.x, mu.y, rx, ry);
    g1[n] = make_float4(A, B, Cc, lop);
    gc[n] = col;
}

// ---------------------------------------------------------------------------
// Pass 2: fused tile kernel. Block = 16x4 pixel tile, 4 waves; wave w owns
// ordered gaussian segment [w*250, (w+1)*250):
//   A) 4 rounds of 64: load precomputed (cx,cy,rx,ry), tile-AABB cull,
//      ballot-compact survivors' eval params into the wave's PRIVATE LDS
//      region (order preserved, no cross-wave sync).
//   B) wave scans its survivors for the tile's 64 pixels (1 px/lane),
//      producing per-segment partials (c_w, T_w).
//   C) one __syncthreads(); wave 0 folds the 4 partials in segment order.
// ---------------------------------------------------------------------------
__global__ __launch_bounds__(256) void splat2d_kernel(
    const float4* __restrict__ g0,
    const float4* __restrict__ g1,
    const float*  __restrict__ gc,
    float* __restrict__ out)
{
    __shared__ float4 s0[NSEG][SEG];   // cx, cy, A, B      (16 KB)
    __shared__ float4 s1[NSEG][SEG];   // C, lop, col, 0    (16 KB)
    __shared__ float2 comb[NSEG][64];  // (c, T) partials; [seg][lane] so both
                                       // the write (w,lane) and the fold read
                                       // (s,lane) are stride-8B (conflict-free)

    const int tid  = threadIdx.x;
    const int lane = tid & 63;
    const int w    = tid >> 6;
    const int tx0  = blockIdx.x * TILE_W;
    const int ty0  = blockIdx.y * TILE_H;

    const float midx = (float)tx0 + 0.5f * (TILE_W - 1) + 0.5f;
    const float midy = (float)ty0 + 0.5f * (TILE_H - 1) + 0.5f;
    const float hx = 0.5f * (TILE_W - 1);
    const float hy = 0.5f * (TILE_H - 1);

    // --- A: per-wave cull + compact into private LDS region ---
    int cnt = 0;
    const int base = w * SEG;
    #pragma unroll
    for (int r = 0; r < 4; ++r) {
        const int o = r * 64 + lane;         // offset within segment
        bool keep = false;
        float4 q0;
        if (o < SEG) {
            q0 = g0[base + o];               // cx, cy, rx, ry (L2-resident)
            keep = (fabsf(q0.x - midx) <= hx + q0.z) &&
                   (fabsf(q0.y - midy) <= hy + q0.w);
        }
        unsigned long long m = __ballot(keep);
        int rank = __popcll(m & ((1ull << lane) - 1ull));
        if (keep) {
            float4 q1 = g1[base + o];        // A, B, C, lop
            float col = gc[base + o];
            s0[w][cnt + rank] = make_float4(q0.x, q0.y, q1.x, q1.y);
            s1[w][cnt + rank] = make_float4(q1.z, q1.w, col, 0.0f);
        }
        cnt += __popcll(m);
    }

    // --- B: per-wave ordered scan over its survivors ---
    const float px = (float)(tx0 + (lane & (TILE_W - 1))) + 0.5f;
    const float py = (float)(ty0 + (lane >> 4)) + 0.5f;

    float T = 1.0f;
    float accum = 0.0f;
    for (int k = 0; k < cnt; ++k) {
        float4 q0 = s0[w][k];
        float4 q1 = s1[w][k];
        float dx = px - q0.x;
        float dy = py - q0.y;
        float t  = fmaf(q0.w, dy, q0.z * dx);               // A*dx + B*dy
        float e  = fmaf(t, dx, fmaf(q1.x * dy, dy, q1.y));  // + C*dy^2 + lop
        float alpha = fminf(__builtin_amdgcn_exp2f(e), ALPHA_MAX);
        accum = fmaf(alpha * T, q1.z, accum);
        T = fmaf(-alpha, T, T);
    }
    comb[w][lane] = make_float2(accum, T);

    // --- C: fold segments in order, store ---
    __syncthreads();
    if (w == 0) {
        float c = 0.0f, Tt = 1.0f;
        #pragma unroll
        for (int s = 0; s < NSEG; ++s) {
            float2 v = comb[s][lane];
            c  = fmaf(Tt, v.x, c);
            Tt *= v.y;
        }
        out[(ty0 + (lane >> 4)) * IW + tx0 + (lane & (TILE_W - 1))] = c;
    }
}

extern "C" void kernel_launch(void* const* d_in, const int* in_sizes, int n_in,
                              void* d_out, int out_size, void* d_ws, size_t ws_size,
                              hipStream_t stream) {
    const float* means     = (const float*)d_in[0];
    const float* quats     = (const float*)d_in[1];
    const float* scales    = (const float*)d_in[2];
    const float* rgbs      = (const float*)d_in[3];
    const float* opacities = (const float*)d_in[4];
    float* out = (float*)d_out;

    // workspace: g0 (16 KB) | g1 (16 KB) | gc (4 KB)  -> 36 KB total
    float4* g0 = (float4*)d_ws;
    float4* g1 = g0 + NG;
    float*  gc = (float*)(g1 + NG);

    precompute_kernel<<<dim3((NG + 255) / 256), 256, 0, stream>>>(
        means, quats, scales, rgbs, opacities, g0, g1, gc);
    splat2d_kernel<<<dim3(TILES_X, TILES_Y), 256, 0, stream>>>(
        g0, g1, gc, out);
}

// Round 2
// 66.640 us; speedup vs baseline: 1.0188x; 1.0188x over previous
//
#include <hip/hip_runtime.h>
#include <math.h>

#define IW 256
#define IH 256
#define NG 1000
#define NSEG 4
#define SEG (NG / NSEG)         // 250 gaussians per wave-segment
#define TILE_W 16
#define TILE_H 4
#define TILES_X (IW / TILE_W)   // 16
#define TILES_Y (IH / TILE_H)   // 64
#define ALPHA_MAX 0.999f
#define LOG2_EPS -19.93157f     // log2(1e-6) cull threshold
#define LN2 0.6931471805599453f
#define INV_LN2 1.4426950408889634f
// Conservative radius factor: r = sqrt(2*a11*t), a11 <= trace = sx^2+sy^2,
// t = ln(op)-ln(1e-6) <= 13.8156  ->  r <= 5.2567*sqrt(sx^2+sy^2)
#define KRAD 5.2567f

// Single fused kernel (one launch — round-1 evidence suggests per-launch
// overhead ~6-10us dwarfs the phase-A compute we removed last round).
// Block = 16x4 pixel tile, 4 waves; wave w owns ordered segment [w*250,(w+1)*250):
//   A1) cheap conservative cull (no transcendentals): 2x 8B loads + AABB vs
//       bound radius; ballot-compact survivor INDICES (order preserved).
//   A2) full param math + exact cull ONLY for A1 survivors (~46/wave ->
//       usually 1 round of 64 instead of 4); compact params into the wave's
//       private LDS region.
//   B) wave scans its survivors for the tile's 64 pixels (1 px/lane).
//   C) one __syncthreads(); wave 0 folds the 4 partials in segment order.
__global__ __launch_bounds__(256) void splat2d_kernel(
    const float* __restrict__ means,
    const float* __restrict__ quats,
    const float* __restrict__ scales,
    const float* __restrict__ rgbs,
    const float* __restrict__ opacities,
    float* __restrict__ out)
{
    __shared__ float4 s0[NSEG][SEG];         // cx, cy, A, B      (16 KB)
    __shared__ float4 s1[NSEG][SEG];         // C, lop, col, 0    (16 KB)
    __shared__ unsigned short sidx[NSEG][SEG]; // A1 survivor idx  (2 KB)
    __shared__ float2 comb[NSEG][64];        // (c,T) partials; [seg][lane]
                                             // so write+fold are stride-8B

    const int tid  = threadIdx.x;
    const int lane = tid & 63;
    const int w    = tid >> 6;
    const int tx0  = blockIdx.x * TILE_W;
    const int ty0  = blockIdx.y * TILE_H;

    const float midx = (float)tx0 + 0.5f * (TILE_W - 1) + 0.5f;
    const float midy = (float)ty0 + 0.5f * (TILE_H - 1) + 0.5f;
    const float hx = 0.5f * (TILE_W - 1);
    const float hy = 0.5f * (TILE_H - 1);

    const unsigned long long ltmask = (1ull << lane) - 1ull;
    const int base = w * SEG;

    // --- A1: cheap conservative cull -> ordered index list ---
    int m0 = 0;
    #pragma unroll
    for (int r = 0; r < 4; ++r) {
        const int o = r * 64 + lane;
        bool k0 = false;
        if (o < SEG) {
            float2 mu = ((const float2*)means)[base + o];
            float2 sc = ((const float2*)scales)[base + o];
            float rmax = KRAD * sqrtf(sc.x * sc.x + sc.y * sc.y);
            k0 = (fabsf(mu.x - midx) <= hx + rmax) &&
                 (fabsf(mu.y - midy) <= hy + rmax);
        }
        unsigned long long m = __ballot(k0);
        int rank = __popcll(m & ltmask);
        if (k0) sidx[w][m0 + rank] = (unsigned short)o;
        m0 += __popcll(m);
    }

    // --- A2: exact params + exact cull for A1 survivors only ---
    int cnt = 0;
    for (int d = 0; d < m0; d += 64) {
        bool keep = false;
        float cx, cy, A, B, Cc, lop, col;
        if (d + lane < m0) {
            const int n = base + (int)sidx[w][d + lane];
            float2 mu = ((const float2*)means)[n];
            float2 sc = ((const float2*)scales)[n];
            float q   = quats[n];
            float opa = opacities[n];
            float rgb = rgbs[n];

            float sq, cq;
            __sincosf(q, &sq, &cq);
            float sx2 = sc.x * sc.x, sy2 = sc.y * sc.y;
            float a11 = cq * cq * sx2 + sq * sq * sy2;
            float a12 = cq * sq * (sx2 - sy2);
            float a22 = sq * sq * sx2 + cq * cq * sy2;
            float det = a11 * a22 - a12 * a12;
            float inv = INV_LN2 / det;
            A   = -0.5f * a22 * inv;
            B   =          a12 * inv;
            Cc  = -0.5f * a11 * inv;
            float op = 1.0f / (1.0f + __expf(-opa));
            lop = __log2f(op);
            col = 1.0f / (1.0f + __expf(-rgb));
            cx = mu.x; cy = mu.y;

            float t  = fmaxf((lop - LOG2_EPS) * LN2, 0.0f);
            float rx = sqrtf(2.0f * a11 * t);
            float ry = sqrtf(2.0f * a22 * t);

            keep = (fabsf(cx - midx) <= hx + rx) &&
                   (fabsf(cy - midy) <= hy + ry);
        }
        unsigned long long m = __ballot(keep);
        int rank = __popcll(m & ltmask);
        if (keep) {
            s0[w][cnt + rank] = make_float4(cx, cy, A, B);
            s1[w][cnt + rank] = make_float4(Cc, lop, col, 0.0f);
        }
        cnt += __popcll(m);
    }

    // --- B: per-wave ordered scan over its survivors ---
    const float px = (float)(tx0 + (lane & (TILE_W - 1))) + 0.5f;
    const float py = (float)(ty0 + (lane >> 4)) + 0.5f;

    float T = 1.0f;
    float accum = 0.0f;
    for (int k = 0; k < cnt; ++k) {
        float4 q0 = s0[w][k];
        float4 q1 = s1[w][k];
        float dx = px - q0.x;
        float dy = py - q0.y;
        float t  = fmaf(q0.w, dy, q0.z * dx);               // A*dx + B*dy
        float e  = fmaf(t, dx, fmaf(q1.x * dy, dy, q1.y));  // + C*dy^2 + lop
        float alpha = fminf(__builtin_amdgcn_exp2f(e), ALPHA_MAX);
        accum = fmaf(alpha * T, q1.z, accum);
        T = fmaf(-alpha, T, T);
    }
    comb[w][lane] = make_float2(accum, T);

    // --- C: fold segments in order, store ---
    __syncthreads();
    if (w == 0) {
        float c = 0.0f, Tt = 1.0f;
        #pragma unroll
        for (int s = 0; s < NSEG; ++s) {
            float2 v = comb[s][lane];
            c  = fmaf(Tt, v.x, c);
            Tt *= v.y;
        }
        out[(ty0 + (lane >> 4)) * IW + tx0 + (lane & (TILE_W - 1))] = c;
    }
}

extern "C" void kernel_launch(void* const* d_in, const int* in_sizes, int n_in,
                              void* d_out, int out_size, void* d_ws, size_t ws_size,
                              hipStream_t stream) {
    const float* means     = (const float*)d_in[0];
    const float* quats     = (const float*)d_in[1];
    const float* scales    = (const float*)d_in[2];
    const float* rgbs      = (const float*)d_in[3];
    const float* opacities = (const float*)d_in[4];
    float* out = (float*)d_out;

    splat2d_kernel<<<dim3(TILES_X, TILES_Y), 256, 0, stream>>>(
        means, quats, scales, rgbs, opacities, out);
}